// Round 9
// baseline (246.752 us; speedup 1.0000x reference)
//
#include <hip/hip_runtime.h>
#include <stdint.h>

// SpatialAttention: B=4, C_in=256, C_out=128, H=W=64 (N=4096)
// R14: R12 (best: 83.9us k_flash) + INDEPENDENT-block occupancy via KV
// quarters. R13 (bigger barrier groups) and R7 (more waves, same barrier
// group) both failed -> the ~44% idle is dependency latency with only 2
// barrier-locked groups/SIMD. Quarters give 4 independent blocks/CU whose
// phases interleave freely. R6's quarter-collapse is structurally blocked
// now: V is reg-direct (no starved LDS buffer), K keeps 1-iter DMA
// lookahead, and XCD pinning (2 quarter-streams = 1.5MB < 4MB L2/XCD)
// keeps re-reads L2-resident under any drift (R12 measured FETCH 10.3MB).
// LDS 36864B -> 4 blocks/CU exactly; launch_bounds(256,4) -> 128-VGPR cap
// (R12 uses 76, no spill). Loop body byte-identical to R12; merge sums 4
// partials (R6's verified merge).

#define B_ 4
#define C_ 256
#define O_ 128
#define N_ 4096

#define AP 72  // proj LDS pitch (bf16 elems)

typedef float v4f __attribute__((ext_vector_type(4)));
typedef short v8s __attribute__((ext_vector_type(8)));
typedef _Float16 v8h __attribute__((ext_vector_type(8)));
typedef uint32_t u32;
typedef unsigned short u16;

__device__ __forceinline__ u16 bf16_rne(float f) {
  u32 u = __builtin_bit_cast(u32, f);
  u += 0x7fffu + ((u >> 16) & 1u);
  return (u16)(u >> 16);
}
__device__ __forceinline__ float bf16_f(u16 s) {
  u32 u = ((u32)s) << 16;
  return __builtin_bit_cast(float, u);
}
__device__ __forceinline__ u16 f16_rne(float f) {
  _Float16 h = (_Float16)f;
  return __builtin_bit_cast(u16, h);
}
__device__ __forceinline__ float f16_f(u16 s) {
  return (float)__builtin_bit_cast(_Float16, s);
}
__device__ __forceinline__ v4f mfma16(v8s a, v8s b, v4f c) {
  return __builtin_amdgcn_mfma_f32_16x16x32_bf16(a, b, c, 0, 0, 0);
}
__device__ __forceinline__ v4f mfma16h(v8h a, v8h b, v4f c) {
  return __builtin_amdgcn_mfma_f32_16x16x32_f16(a, b, c, 0, 0, 0);
}
__device__ __forceinline__ void gl16(const u16* g, u16* l) {
  __builtin_amdgcn_global_load_lds(
      (const __attribute__((address_space(1))) u32*)g,
      (__attribute__((address_space(3))) u32*)l, 16, 0, 0);
}
template <int CTRL>
__device__ __forceinline__ float dppadd(float x) {
  int yi = __builtin_amdgcn_update_dpp(0, __builtin_bit_cast(int, x), CTRL,
                                       0xf, 0xf, true);
  return x + __builtin_bit_cast(float, yi);
}
__device__ __forceinline__ float sum16(float x) {
  x = dppadd<0xB1>(x);   // xor 1
  x = dppadd<0x4E>(x);   // xor 2
  x = dppadd<0x141>(x);  // xor 4 (row_half_mirror)
  x = dppadd<0x140>(x);  // xor 8 (row_mirror)
  return x;
}

// ------------- merged Q/K projection (+V cast on the K instance) ------------
// blocks 0..255: Q = p*Wq+bq -> single fp16 plane. 256..511: K = b*Wk+bk ->
// fp16 plane, plus bf16 cast of b into Vbf [B][C][N].
// GEMM internals: split-bf16 3-pass (err ~1e-4).
__global__ __launch_bounds__(256) void k_proj(
    const float* __restrict__ Xp, const float* __restrict__ Wq,
    const float* __restrict__ bq, const float* __restrict__ Xb,
    const float* __restrict__ Wk, const float* __restrict__ bk,
    u16* __restrict__ Qh, u16* __restrict__ Kh, u16* __restrict__ Vbf) {
  __shared__ __align__(16) short ah[64 * AP];
  __shared__ __align__(16) short al[64 * AP];
  __shared__ __align__(16) short wh[128 * AP];
  __shared__ __align__(16) short wl[128 * AP];
  const int tid = threadIdx.x;
  const int inst = blockIdx.x >> 8;  // 0 = Q, 1 = K (block-uniform)
  const float* X = inst ? Xb : Xp;
  const float* W = inst ? Wk : Wq;
  const float* bias = inst ? bk : bq;
  const int b = (blockIdx.x >> 6) & 3;
  const int n0 = (blockIdx.x & 63) << 6;
  const int w = tid >> 6, lane = tid & 63, l15 = lane & 15, quad = lane >> 4;
  v4f acc[8];
#pragma unroll
  for (int t = 0; t < 8; t++) acc[t] = (v4f){0.f, 0.f, 0.f, 0.f};

  for (int c0 = 0; c0 < C_; c0 += 64) {
    __syncthreads();
    {  // stage A: transpose X[c][n]->lds[n][c], split hi/lo (+ fused V cast)
      const int c = tid >> 2, nch = (tid & 3) << 4;
      const float* s = X + ((size_t)(b * C_ + c0 + c)) * N_ + n0 + nch;
      float4 f0 = ((const float4*)s)[0], f1 = ((const float4*)s)[1],
             f2 = ((const float4*)s)[2], f3 = ((const float4*)s)[3];
      float v[16] = {f0.x, f0.y, f0.z, f0.w, f1.x, f1.y, f1.z, f1.w,
                     f2.x, f2.y, f2.z, f2.w, f3.x, f3.y, f3.z, f3.w};
      u16 hh[16];
#pragma unroll
      for (int j = 0; j < 16; j++) {
        u16 h = bf16_rne(v[j]);
        u16 l = bf16_rne(v[j] - bf16_f(h));
        hh[j] = h;
        ah[(nch + j) * AP + c] = (short)h;
        al[(nch + j) * AP + c] = (short)l;
      }
      if (inst) {
        u32 pk[8];
#pragma unroll
        for (int jj = 0; jj < 8; jj++)
          pk[jj] = (u32)hh[2 * jj] | ((u32)hh[2 * jj + 1] << 16);
        u16* vd = Vbf + ((size_t)(b * C_ + c0 + c)) * N_ + n0 + nch;
        ((uint4*)vd)[0] = make_uint4(pk[0], pk[1], pk[2], pk[3]);
        ((uint4*)vd)[1] = make_uint4(pk[4], pk[5], pk[6], pk[7]);
      }
    }
    {  // stage W chunk [128 o][64 c], split hi/lo
      const int o = tid >> 1, cch = (tid & 1) << 5;
      const float* s = W + (size_t)o * C_ + c0 + cch;
#pragma unroll
      for (int jj = 0; jj < 8; jj++) {
        float4 f = ((const float4*)s)[jj];
        float v[4] = {f.x, f.y, f.z, f.w};
#pragma unroll
        for (int j = 0; j < 4; j++) {
          u16 h = bf16_rne(v[j]);
          u16 l = bf16_rne(v[j] - bf16_f(h));
          wh[o * AP + cch + jj * 4 + j] = (short)h;
          wl[o * AP + cch + jj * 4 + j] = (short)l;
        }
      }
    }
    __syncthreads();
#pragma unroll
    for (int s = 0; s < 2; s++) {
      v8s a_h = *(const v8s*)&ah[(16 * w + l15) * AP + 32 * s + 8 * quad];
      v8s a_l = *(const v8s*)&al[(16 * w + l15) * AP + 32 * s + 8 * quad];
#pragma unroll
      for (int to = 0; to < 8; to++) {
        v8s b_h = *(const v8s*)&wh[(16 * to + l15) * AP + 32 * s + 8 * quad];
        v8s b_l = *(const v8s*)&wl[(16 * to + l15) * AP + 32 * s + 8 * quad];
        acc[to] = mfma16(a_h, b_h, acc[to]);
        acc[to] = mfma16(a_h, b_l, acc[to]);
        acc[to] = mfma16(a_l, b_h, acc[to]);
      }
    }
  }
#pragma unroll
  for (int to = 0; to < 8; to++) {
    const int o = 16 * to + l15;
    const float bv = bias[o];
    u16* dst = inst ? Kh : Qh;
#pragma unroll
    for (int r = 0; r < 4; r++) {
      const int n = n0 + 16 * w + 4 * quad + r;  // C/D row = quad*4+reg
      float v = acc[to][r] + bv;
      const size_t idx = (size_t)(b * N_ + n) * O_ + o;
      dst[idx] = f16_rne(v);
    }
  }
}

// ---------------- fused flash attention (partial over a KV quarter) ---------
// grid 1024 = 4 blocks/CU. Decode: xcd=bid&7 -> (b, quarter-pair); each XCD
// owns two quarter-streams of one batch (1.5MB, L2-resident). 4 waves,
// 32 iters of 32 tokens. QK: wave w owns Q rows 16w..16w+15 (1-pass fp16).
// PV: wave w owns channels 64w..64w+63; V straight from global into
// B-frags; P crosses waves via swizzled LDS tile. Loop body == R12.
__global__ __launch_bounds__(256, 4) void k_flash(
    const u16* __restrict__ Qh, const u16* __restrict__ Khp,
    const u16* __restrict__ Vbf, u16* __restrict__ Opart,
    float* __restrict__ lpart) {
  // shorts: K dbuf [2][32][128] fp16 @0 (8192), P [64][64] swizzled @8192
  //         (4096). Loop high-water 12288 shorts; epilogue outx [256][72]
  //         = 18432 shorts (reused after barrier) -> alloc 18432 = 36864 B
  //         -> 4 blocks/CU (147456 <= 163840).
  __shared__ __align__(16) short smem[18432];
  short* const Pt = smem + 8192;

  const int tid = threadIdx.x;
  const int w = tid >> 6, lane = tid & 63, l15 = lane & 15, quad = lane >> 4;
  const int xcd = blockIdx.x & 7;
  const int b = xcd >> 1;                      // XCD owns one batch...
  const int qhi = xcd & 1;                     // ...and one quarter-pair
  const int q2 = (blockIdx.x >> 3) & 1;
  const int quarter = (qhi << 1) | q2;
  const int qt = blockIdx.x >> 4;
  const int n0 = qt << 6;
  const int tok0 = quarter << 10;
  const int og = (b << 8) + (qt << 2) + quarter;  // merge layout

  const u16* khb = Khp + (size_t)b * N_ * O_;
  const u16* vb = Vbf + (size_t)b * C_ * N_;

  // Q fragments (A-layout: row=lane&15, k=32s+8*quad+j), single fp16
  v8h qh[4];
  {
    const u16* qrh = Qh + (size_t)(b * N_ + n0 + 16 * w + l15) * O_;
#pragma unroll
    for (int s = 0; s < 4; s++) qh[s] = *(const v8h*)(qrh + 32 * s + 8 * quad);
  }

  v4f oacc[16];  // [rw][cg]: rows 16rw+4quad+r, channels 64w+16cg+l15
#pragma unroll
  for (int t = 0; t < 16; t++) oacc[t] = (v4f){0.f, 0.f, 0.f, 0.f};
  float lstate[4] = {0.f, 0.f, 0.f, 0.f};

  auto stage = [&](int mtn, int bi) {  // K only: 2 DMA issues/thread
    const int m0n = tok0 + (mtn << 5);
    short* kd = smem + bi * 4096;
#pragma unroll
    for (int i = 0; i < 2; i++) {  // 4 rows/issue, 8 rows/wave, 32 rows total
      const int R = 8 * w + 4 * i;
      const int rl = R + (lane >> 4);
      const int cg = (lane & 15) ^ (rl & 15);
      gl16(khb + ((size_t)(m0n + rl) << 7) + (cg << 3), (u16*)(kd + (R << 7)));
    }
  };

  // V B-frag base: ch row = 64w+16cg+l15, token col 8*quad
  v8s vfr[4];
  const u16* vbase = vb + (size_t)(64 * w + l15) * N_ + (quad << 3);
  auto loadV = [&](int mtn) {
    const int m0 = tok0 + (mtn << 5);
#pragma unroll
    for (int cg = 0; cg < 4; cg++)
      vfr[cg] = *(const v8s*)(vbase + (size_t)(cg << 4) * N_ + m0);
  };

  stage(0, 0);

#pragma unroll 1
  for (int mt = 0; mt < 32; mt++) {
    const int pr = mt & 1;
    __syncthreads();  // B1: drains vmcnt(0) -> K(mt) staged + visible
    loadV(mt);                               // 4 global loads (oldest)
    if (mt + 1 < 32) stage(mt + 1, 1 - pr);  // 2 DMA (newest)
    const short* kc = smem + pr * 4096;

    // QK: e = qh . k, 1-pass fp16, two acc chains for ILP
    v4f eh[2];
#pragma unroll
    for (int t = 0; t < 2; t++) eh[t] = (v4f){0.f, 0.f, 0.f, 0.f};
#pragma unroll
    for (int s = 0; s < 4; s++) {
#pragma unroll
      for (int t = 0; t < 2; t++) {
        const int off = ((16 * t + l15) << 7) + (((4 * s + quad) ^ l15) << 3);
        const v8h kf = *(const v8h*)&kc[off];
        eh[t] = mfma16h(qh[s], kf, eh[t]);
      }
    }

    // no-max softmax: p=exp(e); write swizzled P; row sums deferred past B2
    float pp[4];
#pragma unroll
    for (int r = 0; r < 4; r++) {
      float p0 = __expf(eh[0][r]);
      float p1 = __expf(eh[1][r]);
      const int row = 16 * w + 4 * quad + r;
      const int sw = (row & 7) << 3;
      Pt[(row << 6) + (l15 ^ sw)] = (short)bf16_rne(p0);
      Pt[(row << 6) + ((16 + l15) ^ sw)] = (short)bf16_rne(p1);
      pp[r] = p0 + p1;
    }
    // B2: P handoff across waves. lgkm-only wait + raw barrier so the
    // staged K prefetch (vmcnt queue) is NOT drained mid-iter.
    __builtin_amdgcn_s_waitcnt(0xC07F);  // lgkmcnt(0)
    asm volatile("s_barrier" ::: "memory");

    // PV channel-split: oacc[rw][cg] += P(rows 16rw) * V(ch 64w+16cg).
    // vfr use -> compiler waits vmcnt(2): V landed, K(mt+1) DMA in flight.
    v8s af[4];
#pragma unroll
    for (int rw = 0; rw < 4; rw++) {
      const int row = (rw << 4) + l15;
      const int col = (quad << 3) ^ ((row & 7) << 3);
      af[rw] = *(const v8s*)&Pt[(row << 6) + col];
    }
#pragma unroll
    for (int cg = 0; cg < 4; cg++)
#pragma unroll
      for (int rw = 0; rw < 4; rw++)
        oacc[rw * 4 + cg] = mfma16(af[rw], vfr[cg], oacc[rw * 4 + cg]);

    // deferred DPP row sums overlap the PV MFMA issue above
#pragma unroll
    for (int r = 0; r < 4; r++) lstate[r] += sum16(pp[r]);
  }

  // epilogue: pack bf16 partial O into LDS [256][72], write l, copy out
  __syncthreads();
  u16* outx = (u16*)smem;  // pitch 72 shorts (144 B, 16B-aligned rows)
#pragma unroll
  for (int rw = 0; rw < 4; rw++)
#pragma unroll
    for (int cg = 0; cg < 4; cg++) {
      const int ch = 64 * w + 16 * cg + l15;
      const v4f o = oacc[rw * 4 + cg];
      u32* q = (u32*)outx;
      const int base = ch * 36 + 8 * rw + 2 * quad;
      q[base] = (u32)bf16_rne(o[0]) | ((u32)bf16_rne(o[1]) << 16);
      q[base + 1] = (u32)bf16_rne(o[2]) | ((u32)bf16_rne(o[3]) << 16);
    }
  if (l15 == 0) {
#pragma unroll
    for (int r = 0; r < 4; r++)
      lpart[(size_t)og * 64 + 16 * w + 4 * quad + r] = lstate[r];
  }
  __syncthreads();
  {
    u16* od = Opart + (size_t)og * 16384;
    const int cr = tid >> 2, nch = (tid & 3) << 4;
#pragma unroll
    for (int it = 0; it < 4; it++) {
      const int c = cr + 64 * it;
      const u16* srcr = &outx[c * 72 + nch];
      uint4* dst = (uint4*)(od + c * 64 + nch);
      dst[0] = ((const uint4*)srcr)[0];
      dst[1] = ((const uint4*)srcr)[1];
    }
  }
}

// ---------------- merge KV quarters: out = (ΣO_i)/(Σl_i) --------------------
__global__ __launch_bounds__(256) void k_merge(const u16* __restrict__ Opart,
                                               const float* __restrict__ lpart,
                                               float* __restrict__ out) {
  const int idx = blockIdx.x * 256 + threadIdx.x;
  const int e4 = idx << 2;  // flat out index: b*2^20 + c*2^12 + n
  const int b = e4 >> 20;
  const int c = (e4 >> 12) & 255;
  const int n = e4 & 4095;
  const int qt = n >> 6, row = n & 63;
  const int g = (b * 64 + qt) * 4;
  const u16* q0 = Opart + (size_t)g * 16384 + c * 64 + row;
  ushort4 a0 = *(const ushort4*)q0;
  ushort4 a1 = *(const ushort4*)(q0 + 16384);
  ushort4 a2 = *(const ushort4*)(q0 + 32768);
  ushort4 a3 = *(const ushort4*)(q0 + 49152);
  const float* lb = lpart + (size_t)g * 64 + row;
  float4 l0 = *(const float4*)lb;
  float4 l1 = *(const float4*)(lb + 64);
  float4 l2 = *(const float4*)(lb + 128);
  float4 l3 = *(const float4*)(lb + 192);
  float4 o;
  o.x = (bf16_f(a0.x) + bf16_f(a1.x) + bf16_f(a2.x) + bf16_f(a3.x)) /
        (l0.x + l1.x + l2.x + l3.x);
  o.y = (bf16_f(a0.y) + bf16_f(a1.y) + bf16_f(a2.y) + bf16_f(a3.y)) /
        (l0.y + l1.y + l2.y + l3.y);
  o.z = (bf16_f(a0.z) + bf16_f(a1.z) + bf16_f(a2.z) + bf16_f(a3.z)) /
        (l0.z + l1.z + l2.z + l3.z);
  o.w = (bf16_f(a0.w) + bf16_f(a1.w) + bf16_f(a2.w) + bf16_f(a3.w)) /
        (l0.w + l1.w + l2.w + l3.w);
  *(float4*)(out + e4) = o;
}

extern "C" void kernel_launch(void* const* d_in, const int* in_sizes, int n_in,
                              void* d_out, int out_size, void* d_ws, size_t ws_size,
                              hipStream_t stream) {
  const float* p = (const float*)d_in[0];
  const float* bb = (const float*)d_in[1];
  const float* Wq = (const float*)d_in[2];
  const float* bq = (const float*)d_in[3];
  const float* Wk = (const float*)d_in[4];
  const float* bk = (const float*)d_in[5];
  float* out = (float*)d_out;

  const size_t plane = (size_t)B_ * N_ * O_;  // 2,097,152 u16
  u16* Qh = (u16*)d_ws;
  u16* Kh = Qh + plane;
  u16* Vbf = Kh + plane;                         // B*C*N u16 = 2 planes
  u16* Opart = Vbf + 2 * plane;                  // 1024*16384 u16 = 33.55 MB
  float* lpart = (float*)(Opart + (size_t)1024 * 16384);  // 1024*64 fp32
  // total ws use ~= 50.6 MB

  hipLaunchKernelGGL(k_proj, dim3(512), dim3(256), 0, stream, p, Wq, bq, bb,
                     Wk, bk, Qh, Kh, Vbf);
  hipLaunchKernelGGL(k_flash, dim3(B_ * 64 * 4), dim3(256), 0, stream, Qh, Kh,
                     Vbf, Opart, lpart);
  hipLaunchKernelGGL(k_merge, dim3((B_ * C_ * N_) / (256 * 4)), dim3(256), 0,
                     stream, Opart, lpart, out);
}

// Round 10
// 185.521 us; speedup vs baseline: 1.3301x; 1.3301x over previous
//
#include <hip/hip_runtime.h>
#include <stdint.h>

// SpatialAttention: B=4, C_in=256, C_out=128, H=W=64 (N=4096)
// R15: R14 with the spill antidote -- ONE token changed:
// __launch_bounds__(256,4) -> (256,2) on k_flash.
// R14 post-mortem: quarters mechanism worked (occupancy 42%, FETCH 21.7MB
// = 12MB unique KV + 16MB Q x4-duplication, no locality collapse) but the
// (256,4) bound squeezed the allocator to 64 VGPRs (body needs 76+) ->
// ~22MB spill (WRITE 55.5MB vs 33.8 real) -> 153us. Third spill from a
// second-arg>=4 bound; empirical toolchain rule: arg=2 only.
// The 2nd arg is a register-allocator occupancy FLOOR, not a runtime
// requirement: with LDS 36864B (4 blocks/CU fit) and 76 VGPRs (16 waves x
// 76 = 1216 <= 2048/CU), (256,2) already PERMITS 4 independent blocks/CU
// at runtime. Everything else byte-identical to R14/R12.

#define B_ 4
#define C_ 256
#define O_ 128
#define N_ 4096

#define AP 72  // proj LDS pitch (bf16 elems)

typedef float v4f __attribute__((ext_vector_type(4)));
typedef short v8s __attribute__((ext_vector_type(8)));
typedef _Float16 v8h __attribute__((ext_vector_type(8)));
typedef uint32_t u32;
typedef unsigned short u16;

__device__ __forceinline__ u16 bf16_rne(float f) {
  u32 u = __builtin_bit_cast(u32, f);
  u += 0x7fffu + ((u >> 16) & 1u);
  return (u16)(u >> 16);
}
__device__ __forceinline__ float bf16_f(u16 s) {
  u32 u = ((u32)s) << 16;
  return __builtin_bit_cast(float, u);
}
__device__ __forceinline__ u16 f16_rne(float f) {
  _Float16 h = (_Float16)f;
  return __builtin_bit_cast(u16, h);
}
__device__ __forceinline__ float f16_f(u16 s) {
  return (float)__builtin_bit_cast(_Float16, s);
}
__device__ __forceinline__ v4f mfma16(v8s a, v8s b, v4f c) {
  return __builtin_amdgcn_mfma_f32_16x16x32_bf16(a, b, c, 0, 0, 0);
}
__device__ __forceinline__ v4f mfma16h(v8h a, v8h b, v4f c) {
  return __builtin_amdgcn_mfma_f32_16x16x32_f16(a, b, c, 0, 0, 0);
}
__device__ __forceinline__ void gl16(const u16* g, u16* l) {
  __builtin_amdgcn_global_load_lds(
      (const __attribute__((address_space(1))) u32*)g,
      (__attribute__((address_space(3))) u32*)l, 16, 0, 0);
}
template <int CTRL>
__device__ __forceinline__ float dppadd(float x) {
  int yi = __builtin_amdgcn_update_dpp(0, __builtin_bit_cast(int, x), CTRL,
                                       0xf, 0xf, true);
  return x + __builtin_bit_cast(float, yi);
}
__device__ __forceinline__ float sum16(float x) {
  x = dppadd<0xB1>(x);   // xor 1
  x = dppadd<0x4E>(x);   // xor 2
  x = dppadd<0x141>(x);  // xor 4 (row_half_mirror)
  x = dppadd<0x140>(x);  // xor 8 (row_mirror)
  return x;
}

// ------------- merged Q/K projection (+V cast on the K instance) ------------
// blocks 0..255: Q = p*Wq+bq -> single fp16 plane. 256..511: K = b*Wk+bk ->
// fp16 plane, plus bf16 cast of b into Vbf [B][C][N].
// GEMM internals: split-bf16 3-pass (err ~1e-4).
__global__ __launch_bounds__(256) void k_proj(
    const float* __restrict__ Xp, const float* __restrict__ Wq,
    const float* __restrict__ bq, const float* __restrict__ Xb,
    const float* __restrict__ Wk, const float* __restrict__ bk,
    u16* __restrict__ Qh, u16* __restrict__ Kh, u16* __restrict__ Vbf) {
  __shared__ __align__(16) short ah[64 * AP];
  __shared__ __align__(16) short al[64 * AP];
  __shared__ __align__(16) short wh[128 * AP];
  __shared__ __align__(16) short wl[128 * AP];
  const int tid = threadIdx.x;
  const int inst = blockIdx.x >> 8;  // 0 = Q, 1 = K (block-uniform)
  const float* X = inst ? Xb : Xp;
  const float* W = inst ? Wk : Wq;
  const float* bias = inst ? bk : bq;
  const int b = (blockIdx.x >> 6) & 3;
  const int n0 = (blockIdx.x & 63) << 6;
  const int w = tid >> 6, lane = tid & 63, l15 = lane & 15, quad = lane >> 4;
  v4f acc[8];
#pragma unroll
  for (int t = 0; t < 8; t++) acc[t] = (v4f){0.f, 0.f, 0.f, 0.f};

  for (int c0 = 0; c0 < C_; c0 += 64) {
    __syncthreads();
    {  // stage A: transpose X[c][n]->lds[n][c], split hi/lo (+ fused V cast)
      const int c = tid >> 2, nch = (tid & 3) << 4;
      const float* s = X + ((size_t)(b * C_ + c0 + c)) * N_ + n0 + nch;
      float4 f0 = ((const float4*)s)[0], f1 = ((const float4*)s)[1],
             f2 = ((const float4*)s)[2], f3 = ((const float4*)s)[3];
      float v[16] = {f0.x, f0.y, f0.z, f0.w, f1.x, f1.y, f1.z, f1.w,
                     f2.x, f2.y, f2.z, f2.w, f3.x, f3.y, f3.z, f3.w};
      u16 hh[16];
#pragma unroll
      for (int j = 0; j < 16; j++) {
        u16 h = bf16_rne(v[j]);
        u16 l = bf16_rne(v[j] - bf16_f(h));
        hh[j] = h;
        ah[(nch + j) * AP + c] = (short)h;
        al[(nch + j) * AP + c] = (short)l;
      }
      if (inst) {
        u32 pk[8];
#pragma unroll
        for (int jj = 0; jj < 8; jj++)
          pk[jj] = (u32)hh[2 * jj] | ((u32)hh[2 * jj + 1] << 16);
        u16* vd = Vbf + ((size_t)(b * C_ + c0 + c)) * N_ + n0 + nch;
        ((uint4*)vd)[0] = make_uint4(pk[0], pk[1], pk[2], pk[3]);
        ((uint4*)vd)[1] = make_uint4(pk[4], pk[5], pk[6], pk[7]);
      }
    }
    {  // stage W chunk [128 o][64 c], split hi/lo
      const int o = tid >> 1, cch = (tid & 1) << 5;
      const float* s = W + (size_t)o * C_ + c0 + cch;
#pragma unroll
      for (int jj = 0; jj < 8; jj++) {
        float4 f = ((const float4*)s)[jj];
        float v[4] = {f.x, f.y, f.z, f.w};
#pragma unroll
        for (int j = 0; j < 4; j++) {
          u16 h = bf16_rne(v[j]);
          u16 l = bf16_rne(v[j] - bf16_f(h));
          wh[o * AP + cch + jj * 4 + j] = (short)h;
          wl[o * AP + cch + jj * 4 + j] = (short)l;
        }
      }
    }
    __syncthreads();
#pragma unroll
    for (int s = 0; s < 2; s++) {
      v8s a_h = *(const v8s*)&ah[(16 * w + l15) * AP + 32 * s + 8 * quad];
      v8s a_l = *(const v8s*)&al[(16 * w + l15) * AP + 32 * s + 8 * quad];
#pragma unroll
      for (int to = 0; to < 8; to++) {
        v8s b_h = *(const v8s*)&wh[(16 * to + l15) * AP + 32 * s + 8 * quad];
        v8s b_l = *(const v8s*)&wl[(16 * to + l15) * AP + 32 * s + 8 * quad];
        acc[to] = mfma16(a_h, b_h, acc[to]);
        acc[to] = mfma16(a_h, b_l, acc[to]);
        acc[to] = mfma16(a_l, b_h, acc[to]);
      }
    }
  }
#pragma unroll
  for (int to = 0; to < 8; to++) {
    const int o = 16 * to + l15;
    const float bv = bias[o];
    u16* dst = inst ? Kh : Qh;
#pragma unroll
    for (int r = 0; r < 4; r++) {
      const int n = n0 + 16 * w + 4 * quad + r;  // C/D row = quad*4+reg
      float v = acc[to][r] + bv;
      const size_t idx = (size_t)(b * N_ + n) * O_ + o;
      dst[idx] = f16_rne(v);
    }
  }
}

// ---------------- fused flash attention (partial over a KV quarter) ---------
// grid 1024; LDS 36864B -> 4 blocks/CU at runtime (launch_bounds(256,2) is
// only the allocator floor; 76 VGPRs x 16 waves fits). Decode: xcd=bid&7 ->
// (b, quarter-pair); each XCD owns two quarter-streams of one batch (1.5MB,
// L2-resident). 4 waves, 32 iters of 32 tokens. Loop body == R12.
__global__ __launch_bounds__(256, 2) void k_flash(
    const u16* __restrict__ Qh, const u16* __restrict__ Khp,
    const u16* __restrict__ Vbf, u16* __restrict__ Opart,
    float* __restrict__ lpart) {
  // shorts: K dbuf [2][32][128] fp16 @0 (8192), P [64][64] swizzled @8192
  //         (4096). Loop high-water 12288 shorts; epilogue outx [256][72]
  //         = 18432 shorts (reused after barrier) -> alloc 18432 = 36864 B
  //         -> 4 blocks/CU (147456 <= 163840).
  __shared__ __align__(16) short smem[18432];
  short* const Pt = smem + 8192;

  const int tid = threadIdx.x;
  const int w = tid >> 6, lane = tid & 63, l15 = lane & 15, quad = lane >> 4;
  const int xcd = blockIdx.x & 7;
  const int b = xcd >> 1;                      // XCD owns one batch...
  const int qhi = xcd & 1;                     // ...and one quarter-pair
  const int q2 = (blockIdx.x >> 3) & 1;
  const int quarter = (qhi << 1) | q2;
  const int qt = blockIdx.x >> 4;
  const int n0 = qt << 6;
  const int tok0 = quarter << 10;
  const int og = (b << 8) + (qt << 2) + quarter;  // merge layout

  const u16* khb = Khp + (size_t)b * N_ * O_;
  const u16* vb = Vbf + (size_t)b * C_ * N_;

  // Q fragments (A-layout: row=lane&15, k=32s+8*quad+j), single fp16
  v8h qh[4];
  {
    const u16* qrh = Qh + (size_t)(b * N_ + n0 + 16 * w + l15) * O_;
#pragma unroll
    for (int s = 0; s < 4; s++) qh[s] = *(const v8h*)(qrh + 32 * s + 8 * quad);
  }

  v4f oacc[16];  // [rw][cg]: rows 16rw+4quad+r, channels 64w+16cg+l15
#pragma unroll
  for (int t = 0; t < 16; t++) oacc[t] = (v4f){0.f, 0.f, 0.f, 0.f};
  float lstate[4] = {0.f, 0.f, 0.f, 0.f};

  auto stage = [&](int mtn, int bi) {  // K only: 2 DMA issues/thread
    const int m0n = tok0 + (mtn << 5);
    short* kd = smem + bi * 4096;
#pragma unroll
    for (int i = 0; i < 2; i++) {  // 4 rows/issue, 8 rows/wave, 32 rows total
      const int R = 8 * w + 4 * i;
      const int rl = R + (lane >> 4);
      const int cg = (lane & 15) ^ (rl & 15);
      gl16(khb + ((size_t)(m0n + rl) << 7) + (cg << 3), (u16*)(kd + (R << 7)));
    }
  };

  // V B-frag base: ch row = 64w+16cg+l15, token col 8*quad
  v8s vfr[4];
  const u16* vbase = vb + (size_t)(64 * w + l15) * N_ + (quad << 3);
  auto loadV = [&](int mtn) {
    const int m0 = tok0 + (mtn << 5);
#pragma unroll
    for (int cg = 0; cg < 4; cg++)
      vfr[cg] = *(const v8s*)(vbase + (size_t)(cg << 4) * N_ + m0);
  };

  stage(0, 0);

#pragma unroll 1
  for (int mt = 0; mt < 32; mt++) {
    const int pr = mt & 1;
    __syncthreads();  // B1: drains vmcnt(0) -> K(mt) staged + visible
    loadV(mt);                               // 4 global loads (oldest)
    if (mt + 1 < 32) stage(mt + 1, 1 - pr);  // 2 DMA (newest)
    const short* kc = smem + pr * 4096;

    // QK: e = qh . k, 1-pass fp16, two acc chains for ILP
    v4f eh[2];
#pragma unroll
    for (int t = 0; t < 2; t++) eh[t] = (v4f){0.f, 0.f, 0.f, 0.f};
#pragma unroll
    for (int s = 0; s < 4; s++) {
#pragma unroll
      for (int t = 0; t < 2; t++) {
        const int off = ((16 * t + l15) << 7) + (((4 * s + quad) ^ l15) << 3);
        const v8h kf = *(const v8h*)&kc[off];
        eh[t] = mfma16h(qh[s], kf, eh[t]);
      }
    }

    // no-max softmax: p=exp(e); write swizzled P; row sums deferred past B2
    float pp[4];
#pragma unroll
    for (int r = 0; r < 4; r++) {
      float p0 = __expf(eh[0][r]);
      float p1 = __expf(eh[1][r]);
      const int row = 16 * w + 4 * quad + r;
      const int sw = (row & 7) << 3;
      Pt[(row << 6) + (l15 ^ sw)] = (short)bf16_rne(p0);
      Pt[(row << 6) + ((16 + l15) ^ sw)] = (short)bf16_rne(p1);
      pp[r] = p0 + p1;
    }
    // B2: P handoff across waves. lgkm-only wait + raw barrier so the
    // staged K prefetch (vmcnt queue) is NOT drained mid-iter.
    __builtin_amdgcn_s_waitcnt(0xC07F);  // lgkmcnt(0)
    asm volatile("s_barrier" ::: "memory");

    // PV channel-split: oacc[rw][cg] += P(rows 16rw) * V(ch 64w+16cg).
    // vfr use -> compiler waits vmcnt(2): V landed, K(mt+1) DMA in flight.
    v8s af[4];
#pragma unroll
    for (int rw = 0; rw < 4; rw++) {
      const int row = (rw << 4) + l15;
      const int col = (quad << 3) ^ ((row & 7) << 3);
      af[rw] = *(const v8s*)&Pt[(row << 6) + col];
    }
#pragma unroll
    for (int cg = 0; cg < 4; cg++)
#pragma unroll
      for (int rw = 0; rw < 4; rw++)
        oacc[rw * 4 + cg] = mfma16(af[rw], vfr[cg], oacc[rw * 4 + cg]);

    // deferred DPP row sums overlap the PV MFMA issue above
#pragma unroll
    for (int r = 0; r < 4; r++) lstate[r] += sum16(pp[r]);
  }

  // epilogue: pack bf16 partial O into LDS [256][72], write l, copy out
  __syncthreads();
  u16* outx = (u16*)smem;  // pitch 72 shorts (144 B, 16B-aligned rows)
#pragma unroll
  for (int rw = 0; rw < 4; rw++)
#pragma unroll
    for (int cg = 0; cg < 4; cg++) {
      const int ch = 64 * w + 16 * cg + l15;
      const v4f o = oacc[rw * 4 + cg];
      u32* q = (u32*)outx;
      const int base = ch * 36 + 8 * rw + 2 * quad;
      q[base] = (u32)bf16_rne(o[0]) | ((u32)bf16_rne(o[1]) << 16);
      q[base + 1] = (u32)bf16_rne(o[2]) | ((u32)bf16_rne(o[3]) << 16);
    }
  if (l15 == 0) {
#pragma unroll
    for (int r = 0; r < 4; r++)
      lpart[(size_t)og * 64 + 16 * w + 4 * quad + r] = lstate[r];
  }
  __syncthreads();
  {
    u16* od = Opart + (size_t)og * 16384;
    const int cr = tid >> 2, nch = (tid & 3) << 4;
#pragma unroll
    for (int it = 0; it < 4; it++) {
      const int c = cr + 64 * it;
      const u16* srcr = &outx[c * 72 + nch];
      uint4* dst = (uint4*)(od + c * 64 + nch);
      dst[0] = ((const uint4*)srcr)[0];
      dst[1] = ((const uint4*)srcr)[1];
    }
  }
}

// ---------------- merge KV quarters: out = (ΣO_i)/(Σl_i) --------------------
__global__ __launch_bounds__(256) void k_merge(const u16* __restrict__ Opart,
                                               const float* __restrict__ lpart,
                                               float* __restrict__ out) {
  const int idx = blockIdx.x * 256 + threadIdx.x;
  const int e4 = idx << 2;  // flat out index: b*2^20 + c*2^12 + n
  const int b = e4 >> 20;
  const int c = (e4 >> 12) & 255;
  const int n = e4 & 4095;
  const int qt = n >> 6, row = n & 63;
  const int g = (b * 64 + qt) * 4;
  const u16* q0 = Opart + (size_t)g * 16384 + c * 64 + row;
  ushort4 a0 = *(const ushort4*)q0;
  ushort4 a1 = *(const ushort4*)(q0 + 16384);
  ushort4 a2 = *(const ushort4*)(q0 + 32768);
  ushort4 a3 = *(const ushort4*)(q0 + 49152);
  const float* lb = lpart + (size_t)g * 64 + row;
  float4 l0 = *(const float4*)lb;
  float4 l1 = *(const float4*)(lb + 64);
  float4 l2 = *(const float4*)(lb + 128);
  float4 l3 = *(const float4*)(lb + 192);
  float4 o;
  o.x = (bf16_f(a0.x) + bf16_f(a1.x) + bf16_f(a2.x) + bf16_f(a3.x)) /
        (l0.x + l1.x + l2.x + l3.x);
  o.y = (bf16_f(a0.y) + bf16_f(a1.y) + bf16_f(a2.y) + bf16_f(a3.y)) /
        (l0.y + l1.y + l2.y + l3.y);
  o.z = (bf16_f(a0.z) + bf16_f(a1.z) + bf16_f(a2.z) + bf16_f(a3.z)) /
        (l0.z + l1.z + l2.z + l3.z);
  o.w = (bf16_f(a0.w) + bf16_f(a1.w) + bf16_f(a2.w) + bf16_f(a3.w)) /
        (l0.w + l1.w + l2.w + l3.w);
  *(float4*)(out + e4) = o;
}

extern "C" void kernel_launch(void* const* d_in, const int* in_sizes, int n_in,
                              void* d_out, int out_size, void* d_ws, size_t ws_size,
                              hipStream_t stream) {
  const float* p = (const float*)d_in[0];
  const float* bb = (const float*)d_in[1];
  const float* Wq = (const float*)d_in[2];
  const float* bq = (const float*)d_in[3];
  const float* Wk = (const float*)d_in[4];
  const float* bk = (const float*)d_in[5];
  float* out = (float*)d_out;

  const size_t plane = (size_t)B_ * N_ * O_;  // 2,097,152 u16
  u16* Qh = (u16*)d_ws;
  u16* Kh = Qh + plane;
  u16* Vbf = Kh + plane;                         // B*C*N u16 = 2 planes
  u16* Opart = Vbf + 2 * plane;                  // 1024*16384 u16 = 33.55 MB
  float* lpart = (float*)(Opart + (size_t)1024 * 16384);  // 1024*64 fp32
  // total ws use ~= 50.6 MB

  hipLaunchKernelGGL(k_proj, dim3(512), dim3(256), 0, stream, p, Wq, bq, bb,
                     Wk, bk, Qh, Kh, Vbf);
  hipLaunchKernelGGL(k_flash, dim3(B_ * 64 * 4), dim3(256), 0, stream, Qh, Kh,
                     Vbf, Opart, lpart);
  hipLaunchKernelGGL(k_merge, dim3((B_ * C_ * N_) / (256 * 4)), dim3(256), 0,
                     stream, Opart, lpart, out);
}

// Round 12
// 175.973 us; speedup vs baseline: 1.4022x; 1.0543x over previous
//
#include <hip/hip_runtime.h>
#include <stdint.h>

// SpatialAttention: B=4, C_in=256, C_out=128, H=W=64 (N=4096)
// R17: bisect of R16's correctness failure (absmax 5.84). R16 bundled
// {token-interleave K staging + v_cvt_pk_bf16_f32 P-pack} with {hoisted
// sum16, setprio}; the first pair corrupted P (denominator math was
// provably intact -> numerator/P path). Analysis couldn't isolate which
// primitive model is wrong -> revert that pair wholesale to R12's proven
// P path (bf16_rne x2, XOR-swizzled, plain token order; absmax 0.03125).
// Keep only the safe subset:
// (1) sum16 DPP reduction hoisted out of the loop: per-iter lstate[r] +=
//     p0+p1 (1 add); 16-lane butterfly ONCE in epilogue (-32 VALU/iter,
//     ~40% of loop VALU; R12 split was VALU 27us > MFMA 21us).
// (2) s_setprio(1) around the PV MFMA cluster.
// Everything else byte-identical to R12 (best flash 83.9us: halves grid
// 512, V-to-regs, XCD (b,h) decode, P XOR swizzle, lgkm-only B2).

#define B_ 4
#define C_ 256
#define O_ 128
#define N_ 4096

#define AP 72  // proj LDS pitch (bf16 elems)

typedef float v4f __attribute__((ext_vector_type(4)));
typedef short v8s __attribute__((ext_vector_type(8)));
typedef _Float16 v8h __attribute__((ext_vector_type(8)));
typedef uint32_t u32;
typedef unsigned short u16;

__device__ __forceinline__ u16 bf16_rne(float f) {
  u32 u = __builtin_bit_cast(u32, f);
  u += 0x7fffu + ((u >> 16) & 1u);
  return (u16)(u >> 16);
}
__device__ __forceinline__ float bf16_f(u16 s) {
  u32 u = ((u32)s) << 16;
  return __builtin_bit_cast(float, u);
}
__device__ __forceinline__ u16 f16_rne(float f) {
  _Float16 h = (_Float16)f;
  return __builtin_bit_cast(u16, h);
}
__device__ __forceinline__ float f16_f(u16 s) {
  return (float)__builtin_bit_cast(_Float16, s);
}
__device__ __forceinline__ v4f mfma16(v8s a, v8s b, v4f c) {
  return __builtin_amdgcn_mfma_f32_16x16x32_bf16(a, b, c, 0, 0, 0);
}
__device__ __forceinline__ v4f mfma16h(v8h a, v8h b, v4f c) {
  return __builtin_amdgcn_mfma_f32_16x16x32_f16(a, b, c, 0, 0, 0);
}
__device__ __forceinline__ void gl16(const u16* g, u16* l) {
  __builtin_amdgcn_global_load_lds(
      (const __attribute__((address_space(1))) u32*)g,
      (__attribute__((address_space(3))) u32*)l, 16, 0, 0);
}
template <int CTRL>
__device__ __forceinline__ float dppadd(float x) {
  int yi = __builtin_amdgcn_update_dpp(0, __builtin_bit_cast(int, x), CTRL,
                                       0xf, 0xf, true);
  return x + __builtin_bit_cast(float, yi);
}
__device__ __forceinline__ float sum16(float x) {
  x = dppadd<0xB1>(x);   // xor 1
  x = dppadd<0x4E>(x);   // xor 2
  x = dppadd<0x141>(x);  // xor 4 (row_half_mirror)
  x = dppadd<0x140>(x);  // xor 8 (row_mirror)
  return x;
}

// ------------- merged Q/K projection (+V cast on the K instance) ------------
// blocks 0..255: Q = p*Wq+bq -> single fp16 plane. 256..511: K = b*Wk+bk ->
// fp16 plane, plus bf16 cast of b into Vbf [B][C][N].
// GEMM internals: split-bf16 3-pass (err ~1e-4).
__global__ __launch_bounds__(256) void k_proj(
    const float* __restrict__ Xp, const float* __restrict__ Wq,
    const float* __restrict__ bq, const float* __restrict__ Xb,
    const float* __restrict__ Wk, const float* __restrict__ bk,
    u16* __restrict__ Qh, u16* __restrict__ Kh, u16* __restrict__ Vbf) {
  __shared__ __align__(16) short ah[64 * AP];
  __shared__ __align__(16) short al[64 * AP];
  __shared__ __align__(16) short wh[128 * AP];
  __shared__ __align__(16) short wl[128 * AP];
  const int tid = threadIdx.x;
  const int inst = blockIdx.x >> 8;  // 0 = Q, 1 = K (block-uniform)
  const float* X = inst ? Xb : Xp;
  const float* W = inst ? Wk : Wq;
  const float* bias = inst ? bk : bq;
  const int b = (blockIdx.x >> 6) & 3;
  const int n0 = (blockIdx.x & 63) << 6;
  const int w = tid >> 6, lane = tid & 63, l15 = lane & 15, quad = lane >> 4;
  v4f acc[8];
#pragma unroll
  for (int t = 0; t < 8; t++) acc[t] = (v4f){0.f, 0.f, 0.f, 0.f};

  for (int c0 = 0; c0 < C_; c0 += 64) {
    __syncthreads();
    {  // stage A: transpose X[c][n]->lds[n][c], split hi/lo (+ fused V cast)
      const int c = tid >> 2, nch = (tid & 3) << 4;
      const float* s = X + ((size_t)(b * C_ + c0 + c)) * N_ + n0 + nch;
      float4 f0 = ((const float4*)s)[0], f1 = ((const float4*)s)[1],
             f2 = ((const float4*)s)[2], f3 = ((const float4*)s)[3];
      float v[16] = {f0.x, f0.y, f0.z, f0.w, f1.x, f1.y, f1.z, f1.w,
                     f2.x, f2.y, f2.z, f2.w, f3.x, f3.y, f3.z, f3.w};
      u16 hh[16];
#pragma unroll
      for (int j = 0; j < 16; j++) {
        u16 h = bf16_rne(v[j]);
        u16 l = bf16_rne(v[j] - bf16_f(h));
        hh[j] = h;
        ah[(nch + j) * AP + c] = (short)h;
        al[(nch + j) * AP + c] = (short)l;
      }
      if (inst) {
        u32 pk[8];
#pragma unroll
        for (int jj = 0; jj < 8; jj++)
          pk[jj] = (u32)hh[2 * jj] | ((u32)hh[2 * jj + 1] << 16);
        u16* vd = Vbf + ((size_t)(b * C_ + c0 + c)) * N_ + n0 + nch;
        ((uint4*)vd)[0] = make_uint4(pk[0], pk[1], pk[2], pk[3]);
        ((uint4*)vd)[1] = make_uint4(pk[4], pk[5], pk[6], pk[7]);
      }
    }
    {  // stage W chunk [128 o][64 c], split hi/lo
      const int o = tid >> 1, cch = (tid & 1) << 5;
      const float* s = W + (size_t)o * C_ + c0 + cch;
#pragma unroll
      for (int jj = 0; jj < 8; jj++) {
        float4 f = ((const float4*)s)[jj];
        float v[4] = {f.x, f.y, f.z, f.w};
#pragma unroll
        for (int j = 0; j < 4; j++) {
          u16 h = bf16_rne(v[j]);
          u16 l = bf16_rne(v[j] - bf16_f(h));
          wh[o * AP + cch + jj * 4 + j] = (short)h;
          wl[o * AP + cch + jj * 4 + j] = (short)l;
        }
      }
    }
    __syncthreads();
#pragma unroll
    for (int s = 0; s < 2; s++) {
      v8s a_h = *(const v8s*)&ah[(16 * w + l15) * AP + 32 * s + 8 * quad];
      v8s a_l = *(const v8s*)&al[(16 * w + l15) * AP + 32 * s + 8 * quad];
#pragma unroll
      for (int to = 0; to < 8; to++) {
        v8s b_h = *(const v8s*)&wh[(16 * to + l15) * AP + 32 * s + 8 * quad];
        v8s b_l = *(const v8s*)&wl[(16 * to + l15) * AP + 32 * s + 8 * quad];
        acc[to] = mfma16(a_h, b_h, acc[to]);
        acc[to] = mfma16(a_h, b_l, acc[to]);
        acc[to] = mfma16(a_l, b_h, acc[to]);
      }
    }
  }
#pragma unroll
  for (int to = 0; to < 8; to++) {
    const int o = 16 * to + l15;
    const float bv = bias[o];
    u16* dst = inst ? Kh : Qh;
#pragma unroll
    for (int r = 0; r < 4; r++) {
      const int n = n0 + 16 * w + 4 * quad + r;  // C/D row = quad*4+reg
      float v = acc[to][r] + bv;
      const size_t idx = (size_t)(b * N_ + n) * O_ + o;
      dst[idx] = f16_rne(v);
    }
  }
}

// ---------------- fused flash attention (partial over a KV half) ------------
// block decoded XCD-aware: xcd=bid&7 -> (b,h)=(xcd>>1, xcd&1): each XCD owns
// one 1.5MB K/V stream (L2-resident). 4 waves. QK: wave w owns Q rows
// 16w..16w+15 (1-pass fp16). PV: wave w owns channels 64w..64w+63; V comes
// straight from global into B-frags; P crosses waves via swizzled LDS tile.
__global__ __launch_bounds__(256, 2) void k_flash(
    const u16* __restrict__ Qh, const u16* __restrict__ Khp,
    const u16* __restrict__ Vbf, u16* __restrict__ Opart,
    float* __restrict__ lpart) {
  // shorts: K dbuf [2][32][128] fp16 @0 (8192), P [64][64] swizzled @8192
  //         (4096). Loop high-water 12288 shorts; epilogue outx [256][72]
  //         = 18432 shorts (reused after barrier) -> alloc 18432 = 36864 B.
  __shared__ __align__(16) short smem[18432];
  short* const Pt = smem + 8192;

  const int tid = threadIdx.x;
  const int w = tid >> 6, lane = tid & 63, l15 = lane & 15, quad = lane >> 4;
  const int xcd = blockIdx.x & 7;
  const int b = xcd >> 1, h = xcd & 1;  // XCD owns one (b, half) stream
  const int qt = blockIdx.x >> 3;
  const int n0 = qt << 6;
  const int tok0 = h << 11;
  const int og = (b << 7) + (qt << 1) + h;  // old linear id (merge layout)

  const u16* khb = Khp + (size_t)b * N_ * O_;
  const u16* vb = Vbf + (size_t)b * C_ * N_;

  // Q fragments (A-layout: row=lane&15, k=32s+8*quad+j), single fp16
  v8h qh[4];
  {
    const u16* qrh = Qh + (size_t)(b * N_ + n0 + 16 * w + l15) * O_;
#pragma unroll
    for (int s = 0; s < 4; s++) qh[s] = *(const v8h*)(qrh + 32 * s + 8 * quad);
  }

  v4f oacc[16];  // [rw][cg]: rows 16rw+4quad+r, channels 64w+16cg+l15
#pragma unroll
  for (int t = 0; t < 16; t++) oacc[t] = (v4f){0.f, 0.f, 0.f, 0.f};
  float lstate[4] = {0.f, 0.f, 0.f, 0.f};  // per-lane partials; one DPP
                                           // butterfly in the epilogue

  auto stage = [&](int mtn, int bi) {  // K only: 2 DMA issues/thread
    const int m0n = tok0 + (mtn << 5);
    short* kd = smem + bi * 4096;
#pragma unroll
    for (int i = 0; i < 2; i++) {  // 4 rows/issue, 8 rows/wave, 32 rows total
      const int R = 8 * w + 4 * i;
      const int rl = R + (lane >> 4);
      const int cg = (lane & 15) ^ (rl & 15);
      gl16(khb + ((size_t)(m0n + rl) << 7) + (cg << 3), (u16*)(kd + (R << 7)));
    }
  };

  // V B-frag base: ch row = 64w+16cg+l15, token col 8*quad
  v8s vfr[4];
  const u16* vbase = vb + (size_t)(64 * w + l15) * N_ + (quad << 3);
  auto loadV = [&](int mtn) {
    const int m0 = tok0 + (mtn << 5);
#pragma unroll
    for (int cg = 0; cg < 4; cg++)
      vfr[cg] = *(const v8s*)(vbase + (size_t)(cg << 4) * N_ + m0);
  };

  stage(0, 0);

#pragma unroll 1
  for (int mt = 0; mt < 64; mt++) {
    const int pr = mt & 1;
    __syncthreads();  // B1: drains vmcnt(0) -> K(mt) staged + visible
    loadV(mt);                               // 4 global loads (oldest)
    if (mt + 1 < 64) stage(mt + 1, 1 - pr);  // 2 DMA (newest)
    const short* kc = smem + pr * 4096;

    // QK: e = qh . k, 1-pass fp16, two acc chains for ILP
    v4f eh[2];
#pragma unroll
    for (int t = 0; t < 2; t++) eh[t] = (v4f){0.f, 0.f, 0.f, 0.f};
#pragma unroll
    for (int s = 0; s < 4; s++) {
#pragma unroll
      for (int t = 0; t < 2; t++) {
        const int off = ((16 * t + l15) << 7) + (((4 * s + quad) ^ l15) << 3);
        const v8h kf = *(const v8h*)&kc[off];
        eh[t] = mfma16h(qh[s], kf, eh[t]);
      }
    }

    // no-max softmax: p=exp(e); write swizzled P; per-lane l partial only
    // (DPP reduction hoisted to epilogue: -32 VALU/iter)
#pragma unroll
    for (int r = 0; r < 4; r++) {
      float p0 = __expf(eh[0][r]);
      float p1 = __expf(eh[1][r]);
      const int row = 16 * w + 4 * quad + r;
      const int sw = (row & 7) << 3;
      Pt[(row << 6) + (l15 ^ sw)] = (short)bf16_rne(p0);
      Pt[(row << 6) + ((16 + l15) ^ sw)] = (short)bf16_rne(p1);
      lstate[r] += p0 + p1;
    }
    // B2: P handoff across waves. lgkm-only wait + raw barrier so the
    // staged K prefetch (vmcnt queue) is NOT drained mid-iter.
    __builtin_amdgcn_s_waitcnt(0xC07F);  // lgkmcnt(0)
    asm volatile("s_barrier" ::: "memory");

    // PV channel-split: oacc[rw][cg] += P(rows 16rw) * V(ch 64w+16cg).
    // vfr use -> compiler waits vmcnt(2): V landed, K(mt+1) DMA in flight.
    v8s af[4];
#pragma unroll
    for (int rw = 0; rw < 4; rw++) {
      const int row = (rw << 4) + l15;
      const int col = (quad << 3) ^ ((row & 7) << 3);
      af[rw] = *(const v8s*)&Pt[(row << 6) + col];
    }
    __builtin_amdgcn_s_setprio(1);
#pragma unroll
    for (int cg = 0; cg < 4; cg++)
#pragma unroll
      for (int rw = 0; rw < 4; rw++)
        oacc[rw * 4 + cg] = mfma16(af[rw], vfr[cg], oacc[rw * 4 + cg]);
    __builtin_amdgcn_s_setprio(0);
  }

  // epilogue: hoisted 16-lane DPP reduction of lstate, then pack bf16
  // partial O into LDS [256][72], write l, copy out
#pragma unroll
  for (int r = 0; r < 4; r++) lstate[r] = sum16(lstate[r]);
  __syncthreads();
  u16* outx = (u16*)smem;  // pitch 72 shorts (144 B, 16B-aligned rows)
#pragma unroll
  for (int rw = 0; rw < 4; rw++)
#pragma unroll
    for (int cg = 0; cg < 4; cg++) {
      const int ch = 64 * w + 16 * cg + l15;
      const v4f o = oacc[rw * 4 + cg];
      u32* q = (u32*)outx;
      const int base = ch * 36 + 8 * rw + 2 * quad;
      q[base] = (u32)bf16_rne(o[0]) | ((u32)bf16_rne(o[1]) << 16);
      q[base + 1] = (u32)bf16_rne(o[2]) | ((u32)bf16_rne(o[3]) << 16);
    }
  if (l15 == 0) {
#pragma unroll
    for (int r = 0; r < 4; r++)
      lpart[(size_t)og * 64 + 16 * w + 4 * quad + r] = lstate[r];
  }
  __syncthreads();
  {
    u16* od = Opart + (size_t)og * 16384;
    const int cr = tid >> 2, nch = (tid & 3) << 4;
#pragma unroll
    for (int it = 0; it < 4; it++) {
      const int c = cr + 64 * it;
      const u16* srcr = &outx[c * 72 + nch];
      uint4* dst = (uint4*)(od + c * 64 + nch);
      dst[0] = ((const uint4*)srcr)[0];
      dst[1] = ((const uint4*)srcr)[1];
    }
  }
}

// ---------------- merge KV halves: out = (O0+O1)/(l0+l1) --------------------
__global__ __launch_bounds__(256) void k_merge(const u16* __restrict__ Opart,
                                               const float* __restrict__ lpart,
                                               float* __restrict__ out) {
  const int idx = blockIdx.x * 256 + threadIdx.x;
  const int e4 = idx << 2;  // flat out index: b*2^20 + c*2^12 + n
  const int b = e4 >> 20;
  const int c = (e4 >> 12) & 255;
  const int n = e4 & 4095;
  const int qt = n >> 6, row = n & 63;
  const int g = (b * 64 + qt) * 2;
  const u16* q0 = Opart + (size_t)g * 16384 + c * 64 + row;
  ushort4 a0 = *(const ushort4*)q0;
  ushort4 a1 = *(const ushort4*)(q0 + 16384);
  float4 l0 = *(const float4*)(lpart + (size_t)g * 64 + row);
  float4 l1 = *(const float4*)(lpart + (size_t)g * 64 + 64 + row);
  float4 o;
  o.x = (bf16_f(a0.x) + bf16_f(a1.x)) / (l0.x + l1.x);
  o.y = (bf16_f(a0.y) + bf16_f(a1.y)) / (l0.y + l1.y);
  o.z = (bf16_f(a0.z) + bf16_f(a1.z)) / (l0.z + l1.z);
  o.w = (bf16_f(a0.w) + bf16_f(a1.w)) / (l0.w + l1.w);
  *(float4*)(out + e4) = o;
}

extern "C" void kernel_launch(void* const* d_in, const int* in_sizes, int n_in,
                              void* d_out, int out_size, void* d_ws, size_t ws_size,
                              hipStream_t stream) {
  const float* p = (const float*)d_in[0];
  const float* bb = (const float*)d_in[1];
  const float* Wq = (const float*)d_in[2];
  const float* bq = (const float*)d_in[3];
  const float* Wk = (const float*)d_in[4];
  const float* bk = (const float*)d_in[5];
  float* out = (float*)d_out;

  const size_t plane = (size_t)B_ * N_ * O_;  // 2,097,152 u16
  u16* Qh = (u16*)d_ws;
  u16* Kh = Qh + plane;
  u16* Vbf = Kh + plane;                         // B*C*N u16 = 2 planes
  u16* Opart = Vbf + 2 * plane;                  // 512*16384 u16 = 16.78 MB
  float* lpart = (float*)(Opart + (size_t)512 * 16384);  // 512*64 fp32
  // total ws use ~= 33.4 MB

  hipLaunchKernelGGL(k_proj, dim3(512), dim3(256), 0, stream, p, Wq, bq, bb,
                     Wk, bk, Qh, Kh, Vbf);
  hipLaunchKernelGGL(k_flash, dim3(B_ * 64 * 2), dim3(256), 0, stream, Qh, Kh,
                     Vbf, Opart, lpart);
  hipLaunchKernelGGL(k_merge, dim3((B_ * C_ * N_) / (256 * 4)), dim3(256), 0,
                     stream, Opart, lpart, out);
}

// Round 13
// 172.616 us; speedup vs baseline: 1.4295x; 1.0194x over previous
//
#include <hip/hip_runtime.h>
#include <stdint.h>

// SpatialAttention: B=4, C_in=256, C_out=128, H=W=64 (N=4096)
// R18: R17 (best, 175.97us; flash pinned at ~84us -- every cheap axis
// measured/falsified: waves R7, tiles R13, barriers R9/R10, pipes R17,
// occupancy R14/R15) + proj slimming. Q/K are stored as SINGLE fp16
// (R11), so proj's 3-pass split-bf16 GEMM is precision thrown away.
// Single-pass f16 GEMM: input rounding 2^-11 -> q error ~1e-3 relative,
// ~2x the existing f16 output quantization; softmax common-mode cancels.
// k_proj changes only (flash/merge byte-identical to R17):
// - drop al/wl hi/lo planes: LDS 55->27.6KB, staging VALU/elem ~8 -> ~2
//   (V's bf16 cast kept on the K instance).
// - MFMA per c-chunk 48 -> 16 (mfma16h, fp32 acc).
// absmax tripwire: expect <=0.0625 vs threshold 0.101; revert if tripped.

#define B_ 4
#define C_ 256
#define O_ 128
#define N_ 4096

#define AP 72  // proj LDS pitch (f16 elems)

typedef float v4f __attribute__((ext_vector_type(4)));
typedef short v8s __attribute__((ext_vector_type(8)));
typedef _Float16 v8h __attribute__((ext_vector_type(8)));
typedef uint32_t u32;
typedef unsigned short u16;

__device__ __forceinline__ u16 bf16_rne(float f) {
  u32 u = __builtin_bit_cast(u32, f);
  u += 0x7fffu + ((u >> 16) & 1u);
  return (u16)(u >> 16);
}
__device__ __forceinline__ float bf16_f(u16 s) {
  u32 u = ((u32)s) << 16;
  return __builtin_bit_cast(float, u);
}
__device__ __forceinline__ u16 f16_rne(float f) {
  _Float16 h = (_Float16)f;
  return __builtin_bit_cast(u16, h);
}
__device__ __forceinline__ float f16_f(u16 s) {
  return (float)__builtin_bit_cast(_Float16, s);
}
__device__ __forceinline__ v4f mfma16(v8s a, v8s b, v4f c) {
  return __builtin_amdgcn_mfma_f32_16x16x32_bf16(a, b, c, 0, 0, 0);
}
__device__ __forceinline__ v4f mfma16h(v8h a, v8h b, v4f c) {
  return __builtin_amdgcn_mfma_f32_16x16x32_f16(a, b, c, 0, 0, 0);
}
__device__ __forceinline__ void gl16(const u16* g, u16* l) {
  __builtin_amdgcn_global_load_lds(
      (const __attribute__((address_space(1))) u32*)g,
      (__attribute__((address_space(3))) u32*)l, 16, 0, 0);
}
template <int CTRL>
__device__ __forceinline__ float dppadd(float x) {
  int yi = __builtin_amdgcn_update_dpp(0, __builtin_bit_cast(int, x), CTRL,
                                       0xf, 0xf, true);
  return x + __builtin_bit_cast(float, yi);
}
__device__ __forceinline__ float sum16(float x) {
  x = dppadd<0xB1>(x);   // xor 1
  x = dppadd<0x4E>(x);   // xor 2
  x = dppadd<0x141>(x);  // xor 4 (row_half_mirror)
  x = dppadd<0x140>(x);  // xor 8 (row_mirror)
  return x;
}

// ------------- merged Q/K projection (+V cast on the K instance) ------------
// blocks 0..255: Q = p*Wq+bq -> single fp16 plane. 256..511: K = b*Wk+bk ->
// fp16 plane, plus bf16 cast of b into Vbf [B][C][N].
// GEMM: single-pass f16 (inputs rounded to f16, fp32 accumulate).
__global__ __launch_bounds__(256) void k_proj(
    const float* __restrict__ Xp, const float* __restrict__ Wq,
    const float* __restrict__ bq, const float* __restrict__ Xb,
    const float* __restrict__ Wk, const float* __restrict__ bk,
    u16* __restrict__ Qh, u16* __restrict__ Kh, u16* __restrict__ Vbf) {
  __shared__ __align__(16) short ah[64 * AP];
  __shared__ __align__(16) short wh[128 * AP];
  const int tid = threadIdx.x;
  const int inst = blockIdx.x >> 8;  // 0 = Q, 1 = K (block-uniform)
  const float* X = inst ? Xb : Xp;
  const float* W = inst ? Wk : Wq;
  const float* bias = inst ? bk : bq;
  const int b = (blockIdx.x >> 6) & 3;
  const int n0 = (blockIdx.x & 63) << 6;
  const int w = tid >> 6, lane = tid & 63, l15 = lane & 15, quad = lane >> 4;
  v4f acc[8];
#pragma unroll
  for (int t = 0; t < 8; t++) acc[t] = (v4f){0.f, 0.f, 0.f, 0.f};

  for (int c0 = 0; c0 < C_; c0 += 64) {
    __syncthreads();
    {  // stage A: transpose X[c][n]->lds[n][c] as f16 (+ fused V bf16 cast)
      const int c = tid >> 2, nch = (tid & 3) << 4;
      const float* s = X + ((size_t)(b * C_ + c0 + c)) * N_ + n0 + nch;
      float4 f0 = ((const float4*)s)[0], f1 = ((const float4*)s)[1],
             f2 = ((const float4*)s)[2], f3 = ((const float4*)s)[3];
      float v[16] = {f0.x, f0.y, f0.z, f0.w, f1.x, f1.y, f1.z, f1.w,
                     f2.x, f2.y, f2.z, f2.w, f3.x, f3.y, f3.z, f3.w};
#pragma unroll
      for (int j = 0; j < 16; j++) ah[(nch + j) * AP + c] = (short)f16_rne(v[j]);
      if (inst) {
        u32 pk[8];
#pragma unroll
        for (int jj = 0; jj < 8; jj++) {
          u16 h0 = bf16_rne(v[2 * jj]);
          u16 h1 = bf16_rne(v[2 * jj + 1]);
          pk[jj] = (u32)h0 | ((u32)h1 << 16);
        }
        u16* vd = Vbf + ((size_t)(b * C_ + c0 + c)) * N_ + n0 + nch;
        ((uint4*)vd)[0] = make_uint4(pk[0], pk[1], pk[2], pk[3]);
        ((uint4*)vd)[1] = make_uint4(pk[4], pk[5], pk[6], pk[7]);
      }
    }
    {  // stage W chunk [128 o][64 c] as f16
      const int o = tid >> 1, cch = (tid & 1) << 5;
      const float* s = W + (size_t)o * C_ + c0 + cch;
#pragma unroll
      for (int jj = 0; jj < 8; jj++) {
        float4 f = ((const float4*)s)[jj];
        wh[o * AP + cch + jj * 4 + 0] = (short)f16_rne(f.x);
        wh[o * AP + cch + jj * 4 + 1] = (short)f16_rne(f.y);
        wh[o * AP + cch + jj * 4 + 2] = (short)f16_rne(f.z);
        wh[o * AP + cch + jj * 4 + 3] = (short)f16_rne(f.w);
      }
    }
    __syncthreads();
#pragma unroll
    for (int s = 0; s < 2; s++) {
      v8h a_h = *(const v8h*)&ah[(16 * w + l15) * AP + 32 * s + 8 * quad];
#pragma unroll
      for (int to = 0; to < 8; to++) {
        v8h b_h = *(const v8h*)&wh[(16 * to + l15) * AP + 32 * s + 8 * quad];
        acc[to] = mfma16h(a_h, b_h, acc[to]);
      }
    }
  }
#pragma unroll
  for (int to = 0; to < 8; to++) {
    const int o = 16 * to + l15;
    const float bv = bias[o];
    u16* dst = inst ? Kh : Qh;
#pragma unroll
    for (int r = 0; r < 4; r++) {
      const int n = n0 + 16 * w + 4 * quad + r;  // C/D row = quad*4+reg
      float v = acc[to][r] + bv;
      const size_t idx = (size_t)(b * N_ + n) * O_ + o;
      dst[idx] = f16_rne(v);
    }
  }
}

// ---------------- fused flash attention (partial over a KV half) ------------
// block decoded XCD-aware: xcd=bid&7 -> (b,h)=(xcd>>1, xcd&1): each XCD owns
// one 1.5MB K/V stream (L2-resident). 4 waves. QK: wave w owns Q rows
// 16w..16w+15 (1-pass fp16). PV: wave w owns channels 64w..64w+63; V comes
// straight from global into B-frags; P crosses waves via swizzled LDS tile.
__global__ __launch_bounds__(256, 2) void k_flash(
    const u16* __restrict__ Qh, const u16* __restrict__ Khp,
    const u16* __restrict__ Vbf, u16* __restrict__ Opart,
    float* __restrict__ lpart) {
  // shorts: K dbuf [2][32][128] fp16 @0 (8192), P [64][64] swizzled @8192
  //         (4096). Loop high-water 12288 shorts; epilogue outx [256][72]
  //         = 18432 shorts (reused after barrier) -> alloc 18432 = 36864 B.
  __shared__ __align__(16) short smem[18432];
  short* const Pt = smem + 8192;

  const int tid = threadIdx.x;
  const int w = tid >> 6, lane = tid & 63, l15 = lane & 15, quad = lane >> 4;
  const int xcd = blockIdx.x & 7;
  const int b = xcd >> 1, h = xcd & 1;  // XCD owns one (b, half) stream
  const int qt = blockIdx.x >> 3;
  const int n0 = qt << 6;
  const int tok0 = h << 11;
  const int og = (b << 7) + (qt << 1) + h;  // old linear id (merge layout)

  const u16* khb = Khp + (size_t)b * N_ * O_;
  const u16* vb = Vbf + (size_t)b * C_ * N_;

  // Q fragments (A-layout: row=lane&15, k=32s+8*quad+j), single fp16
  v8h qh[4];
  {
    const u16* qrh = Qh + (size_t)(b * N_ + n0 + 16 * w + l15) * O_;
#pragma unroll
    for (int s = 0; s < 4; s++) qh[s] = *(const v8h*)(qrh + 32 * s + 8 * quad);
  }

  v4f oacc[16];  // [rw][cg]: rows 16rw+4quad+r, channels 64w+16cg+l15
#pragma unroll
  for (int t = 0; t < 16; t++) oacc[t] = (v4f){0.f, 0.f, 0.f, 0.f};
  float lstate[4] = {0.f, 0.f, 0.f, 0.f};  // per-lane partials; one DPP
                                           // butterfly in the epilogue

  auto stage = [&](int mtn, int bi) {  // K only: 2 DMA issues/thread
    const int m0n = tok0 + (mtn << 5);
    short* kd = smem + bi * 4096;
#pragma unroll
    for (int i = 0; i < 2; i++) {  // 4 rows/issue, 8 rows/wave, 32 rows total
      const int R = 8 * w + 4 * i;
      const int rl = R + (lane >> 4);
      const int cg = (lane & 15) ^ (rl & 15);
      gl16(khb + ((size_t)(m0n + rl) << 7) + (cg << 3), (u16*)(kd + (R << 7)));
    }
  };

  // V B-frag base: ch row = 64w+16cg+l15, token col 8*quad
  v8s vfr[4];
  const u16* vbase = vb + (size_t)(64 * w + l15) * N_ + (quad << 3);
  auto loadV = [&](int mtn) {
    const int m0 = tok0 + (mtn << 5);
#pragma unroll
    for (int cg = 0; cg < 4; cg++)
      vfr[cg] = *(const v8s*)(vbase + (size_t)(cg << 4) * N_ + m0);
  };

  stage(0, 0);

#pragma unroll 1
  for (int mt = 0; mt < 64; mt++) {
    const int pr = mt & 1;
    __syncthreads();  // B1: drains vmcnt(0) -> K(mt) staged + visible
    loadV(mt);                               // 4 global loads (oldest)
    if (mt + 1 < 64) stage(mt + 1, 1 - pr);  // 2 DMA (newest)
    const short* kc = smem + pr * 4096;

    // QK: e = qh . k, 1-pass fp16, two acc chains for ILP
    v4f eh[2];
#pragma unroll
    for (int t = 0; t < 2; t++) eh[t] = (v4f){0.f, 0.f, 0.f, 0.f};
#pragma unroll
    for (int s = 0; s < 4; s++) {
#pragma unroll
      for (int t = 0; t < 2; t++) {
        const int off = ((16 * t + l15) << 7) + (((4 * s + quad) ^ l15) << 3);
        const v8h kf = *(const v8h*)&kc[off];
        eh[t] = mfma16h(qh[s], kf, eh[t]);
      }
    }

    // no-max softmax: p=exp(e); write swizzled P; per-lane l partial only
    // (DPP reduction hoisted to epilogue: -32 VALU/iter)
#pragma unroll
    for (int r = 0; r < 4; r++) {
      float p0 = __expf(eh[0][r]);
      float p1 = __expf(eh[1][r]);
      const int row = 16 * w + 4 * quad + r;
      const int sw = (row & 7) << 3;
      Pt[(row << 6) + (l15 ^ sw)] = (short)bf16_rne(p0);
      Pt[(row << 6) + ((16 + l15) ^ sw)] = (short)bf16_rne(p1);
      lstate[r] += p0 + p1;
    }
    // B2: P handoff across waves. lgkm-only wait + raw barrier so the
    // staged K prefetch (vmcnt queue) is NOT drained mid-iter.
    __builtin_amdgcn_s_waitcnt(0xC07F);  // lgkmcnt(0)
    asm volatile("s_barrier" ::: "memory");

    // PV channel-split: oacc[rw][cg] += P(rows 16rw) * V(ch 64w+16cg).
    // vfr use -> compiler waits vmcnt(2): V landed, K(mt+1) DMA in flight.
    v8s af[4];
#pragma unroll
    for (int rw = 0; rw < 4; rw++) {
      const int row = (rw << 4) + l15;
      const int col = (quad << 3) ^ ((row & 7) << 3);
      af[rw] = *(const v8s*)&Pt[(row << 6) + col];
    }
    __builtin_amdgcn_s_setprio(1);
#pragma unroll
    for (int cg = 0; cg < 4; cg++)
#pragma unroll
      for (int rw = 0; rw < 4; rw++)
        oacc[rw * 4 + cg] = mfma16(af[rw], vfr[cg], oacc[rw * 4 + cg]);
    __builtin_amdgcn_s_setprio(0);
  }

  // epilogue: hoisted 16-lane DPP reduction of lstate, then pack bf16
  // partial O into LDS [256][72], write l, copy out
#pragma unroll
  for (int r = 0; r < 4; r++) lstate[r] = sum16(lstate[r]);
  __syncthreads();
  u16* outx = (u16*)smem;  // pitch 72 shorts (144 B, 16B-aligned rows)
#pragma unroll
  for (int rw = 0; rw < 4; rw++)
#pragma unroll
    for (int cg = 0; cg < 4; cg++) {
      const int ch = 64 * w + 16 * cg + l15;
      const v4f o = oacc[rw * 4 + cg];
      u32* q = (u32*)outx;
      const int base = ch * 36 + 8 * rw + 2 * quad;
      q[base] = (u32)bf16_rne(o[0]) | ((u32)bf16_rne(o[1]) << 16);
      q[base + 1] = (u32)bf16_rne(o[2]) | ((u32)bf16_rne(o[3]) << 16);
    }
  if (l15 == 0) {
#pragma unroll
    for (int r = 0; r < 4; r++)
      lpart[(size_t)og * 64 + 16 * w + 4 * quad + r] = lstate[r];
  }
  __syncthreads();
  {
    u16* od = Opart + (size_t)og * 16384;
    const int cr = tid >> 2, nch = (tid & 3) << 4;
#pragma unroll
    for (int it = 0; it < 4; it++) {
      const int c = cr + 64 * it;
      const u16* srcr = &outx[c * 72 + nch];
      uint4* dst = (uint4*)(od + c * 64 + nch);
      dst[0] = ((const uint4*)srcr)[0];
      dst[1] = ((const uint4*)srcr)[1];
    }
  }
}

// ---------------- merge KV halves: out = (O0+O1)/(l0+l1) --------------------
__global__ __launch_bounds__(256) void k_merge(const u16* __restrict__ Opart,
                                               const float* __restrict__ lpart,
                                               float* __restrict__ out) {
  const int idx = blockIdx.x * 256 + threadIdx.x;
  const int e4 = idx << 2;  // flat out index: b*2^20 + c*2^12 + n
  const int b = e4 >> 20;
  const int c = (e4 >> 12) & 255;
  const int n = e4 & 4095;
  const int qt = n >> 6, row = n & 63;
  const int g = (b * 64 + qt) * 2;
  const u16* q0 = Opart + (size_t)g * 16384 + c * 64 + row;
  ushort4 a0 = *(const ushort4*)q0;
  ushort4 a1 = *(const ushort4*)(q0 + 16384);
  float4 l0 = *(const float4*)(lpart + (size_t)g * 64 + row);
  float4 l1 = *(const float4*)(lpart + (size_t)g * 64 + 64 + row);
  float4 o;
  o.x = (bf16_f(a0.x) + bf16_f(a1.x)) / (l0.x + l1.x);
  o.y = (bf16_f(a0.y) + bf16_f(a1.y)) / (l0.y + l1.y);
  o.z = (bf16_f(a0.z) + bf16_f(a1.z)) / (l0.z + l1.z);
  o.w = (bf16_f(a0.w) + bf16_f(a1.w)) / (l0.w + l1.w);
  *(float4*)(out + e4) = o;
}

extern "C" void kernel_launch(void* const* d_in, const int* in_sizes, int n_in,
                              void* d_out, int out_size, void* d_ws, size_t ws_size,
                              hipStream_t stream) {
  const float* p = (const float*)d_in[0];
  const float* bb = (const float*)d_in[1];
  const float* Wq = (const float*)d_in[2];
  const float* bq = (const float*)d_in[3];
  const float* Wk = (const float*)d_in[4];
  const float* bk = (const float*)d_in[5];
  float* out = (float*)d_out;

  const size_t plane = (size_t)B_ * N_ * O_;  // 2,097,152 u16
  u16* Qh = (u16*)d_ws;
  u16* Kh = Qh + plane;
  u16* Vbf = Kh + plane;                         // B*C*N u16 = 2 planes
  u16* Opart = Vbf + 2 * plane;                  // 512*16384 u16 = 16.78 MB
  float* lpart = (float*)(Opart + (size_t)512 * 16384);  // 512*64 fp32
  // total ws use ~= 33.4 MB

  hipLaunchKernelGGL(k_proj, dim3(512), dim3(256), 0, stream, p, Wq, bq, bb,
                     Wk, bk, Qh, Kh, Vbf);
  hipLaunchKernelGGL(k_flash, dim3(B_ * 64 * 2), dim3(256), 0, stream, Qh, Kh,
                     Vbf, Opart, lpart);
  hipLaunchKernelGGL(k_merge, dim3((B_ * C_ * N_) / (256 * 4)), dim3(256), 0,
                     stream, Opart, lpart, out);
}